// Round 20
// baseline (433.845 us; speedup 1.0000x reference)
//
#include <hip/hip_runtime.h>
#include <hip/hip_bf16.h>
#include <type_traits>

typedef __attribute__((ext_vector_type(8))) short short8;
typedef __attribute__((ext_vector_type(4))) float f32x4;
using bf16 = __hip_bfloat16;

#define T_SEQ 2048
#define NH 32
#define SCALE_F 0.07216878364870323f   // 192^-0.5

__device__ inline unsigned short f2bf(float f) {
    unsigned u = __builtin_bit_cast(unsigned, f);
    return (unsigned short)((u + 0x7fffu + ((u >> 16) & 1u)) >> 16);
}

__device__ inline void gload_lds16(const void* g, void* l) {
    __builtin_amdgcn_global_load_lds(
        (const __attribute__((address_space(1))) unsigned*)g,
        (__attribute__((address_space(3))) unsigned*)l, 16, 0, 0);
}

__device__ inline void cvt8(const float* in, bf16* out, long v, float scale) {
    f32x4 a = *(const f32x4*)(in + v * 8), b = *(const f32x4*)(in + v * 8 + 4);
    short8 r;
    r[0] = (short)f2bf(a[0] * scale); r[1] = (short)f2bf(a[1] * scale);
    r[2] = (short)f2bf(a[2] * scale); r[3] = (short)f2bf(a[3] * scale);
    r[4] = (short)f2bf(b[0] * scale); r[5] = (short)f2bf(b[1] * scale);
    r[6] = (short)f2bf(b[2] * scale); r[7] = (short)f2bf(b[3] * scale);
    *(short8*)(out + v * 8) = r;
}

// ---------------------------------------------------------------------------
// 8-phase 256x256 GEMM (m201 template port): C[M,N] = A[M,K] * B^T.
// BK=64, 8 waves (512 thr), 128 KB dynamic LDS.
// ---------------------------------------------------------------------------
template <typename TC>
__global__ __launch_bounds__(512, 2) void gemm8p_kernel(
    const bf16* __restrict__ A, const bf16* __restrict__ B, TC* __restrict__ C,
    int K, int lda, int ldb, int ldc)
{
    extern __shared__ char Lds[];   // 131072 bytes
    const int bm = blockIdx.y * 256, bn = blockIdx.x * 256;
    const int tid = threadIdx.x, lane = tid & 63, w = tid >> 6;
    const int l15 = lane & 15, lg = lane >> 4;
    const int wmr = (w >> 2) * 64;
    const int wnc = (w & 3) * 32;
    const int lrh = lane >> 3;
    const int scolb = ((lane & 7) * 16) ^ ((lane >> 3) << 4);
    const int rdswz = (l15 & 7) << 4;
    const bf16* Ab = A + (long)bm * lda;
    const bf16* Bb = B + (long)bn * ldb;
    const int nt = K >> 6;

    auto stage_half = [&](int tt, int isB, int h) {
        const int buf = tt & 1;
        const int k0 = (tt >= nt ? tt - nt : tt) << 6;
        const bf16* Base = isB ? Bb : Ab;
        const int ld = isB ? ldb : lda;
        const char* g = (const char*)Base
            + ((long)(h * 128 + w * 8 + lrh) * ld + k0) * 2 + scolb;
        char* l = Lds + buf * 65536 + isB * 32768 + h * 16384 + w * 1024;
        gload_lds16(g, l);
        gload_lds16(g + (long)128 * ld, l + 8192);
    };

    f32x4 acc[4][4][2] = {};
    stage_half(0, 0, 0); stage_half(0, 1, 1); stage_half(0, 0, 1);
    stage_half(0, 1, 0); stage_half(1, 0, 0); stage_half(1, 1, 1);
    asm volatile("s_waitcnt vmcnt(4)" ::: "memory");
    __builtin_amdgcn_s_barrier();

    for (int t = 0; t < nt; ++t) {
        const char* Bufp = Lds + (t & 1) * 65536;
        short8 aF[4][2], bF[2][2];
        #define ARD(mh, fi, ks) \
            (*(const short8*)(Bufp + (mh) * 16384 + (wmr + (fi) * 16 + l15) * 128 \
                              + (((ks) * 64 + lg * 16) ^ rdswz)))
        #define BRD(nh, nj, ks) \
            (*(const short8*)(Bufp + 32768 + (nh) * 16384 + (wnc + (nj) * 16 + l15) * 128 \
                              + (((ks) * 64 + lg * 16) ^ rdswz)))
        #define MFMA16(q) \
            __builtin_amdgcn_s_setprio(1); \
            _Pragma("unroll") for (int ks = 0; ks < 2; ++ks) \
            _Pragma("unroll") for (int fi = 0; fi < 4; ++fi) \
            _Pragma("unroll") for (int nj = 0; nj < 2; ++nj) \
                acc[q][fi][nj] = __builtin_amdgcn_mfma_f32_16x16x32_bf16( \
                    aF[fi][ks], bF[nj][ks], acc[q][fi][nj], 0, 0, 0); \
            __builtin_amdgcn_s_setprio(0);

        #pragma unroll
        for (int fi = 0; fi < 4; ++fi) { aF[fi][0] = ARD(0, fi, 0); aF[fi][1] = ARD(0, fi, 1); }
        #pragma unroll
        for (int nj = 0; nj < 2; ++nj) { bF[nj][0] = BRD(0, nj, 0); bF[nj][1] = BRD(0, nj, 1); }
        stage_half(t + 1, 0, 1);
        asm volatile("s_waitcnt lgkmcnt(8)" ::: "memory");
        __builtin_amdgcn_s_barrier();
        asm volatile("s_waitcnt lgkmcnt(0)" ::: "memory");
        __builtin_amdgcn_sched_barrier(0);
        MFMA16(0)
        __builtin_amdgcn_s_barrier();
        #pragma unroll
        for (int nj = 0; nj < 2; ++nj) { bF[nj][0] = BRD(1, nj, 0); bF[nj][1] = BRD(1, nj, 1); }
        stage_half(t + 1, 1, 0);
        __builtin_amdgcn_s_barrier();
        asm volatile("s_waitcnt lgkmcnt(0)" ::: "memory");
        __builtin_amdgcn_sched_barrier(0);
        MFMA16(1)
        __builtin_amdgcn_s_barrier();
        #pragma unroll
        for (int fi = 0; fi < 4; ++fi) { aF[fi][0] = ARD(1, fi, 0); aF[fi][1] = ARD(1, fi, 1); }
        stage_half(t + 2, 0, 0);
        __builtin_amdgcn_s_barrier();
        asm volatile("s_waitcnt lgkmcnt(0)" ::: "memory");
        __builtin_amdgcn_sched_barrier(0);
        MFMA16(2)
        __builtin_amdgcn_s_barrier();
        #pragma unroll
        for (int nj = 0; nj < 2; ++nj) { bF[nj][0] = BRD(0, nj, 0); bF[nj][1] = BRD(0, nj, 1); }
        stage_half(t + 2, 1, 1);
        __builtin_amdgcn_s_barrier();
        asm volatile("s_waitcnt lgkmcnt(0)" ::: "memory");
        __builtin_amdgcn_sched_barrier(0);
        MFMA16(3)
        asm volatile("s_waitcnt vmcnt(4)" ::: "memory");
        __builtin_amdgcn_s_barrier();
        #undef ARD
        #undef BRD
        #undef MFMA16
    }
    asm volatile("s_waitcnt vmcnt(0)" ::: "memory");
    const int QMH[4] = {0, 0, 1, 1}, QNH[4] = {0, 1, 1, 0};
    #pragma unroll
    for (int q = 0; q < 4; ++q)
        #pragma unroll
        for (int fi = 0; fi < 4; ++fi)
            #pragma unroll
            for (int nj = 0; nj < 2; ++nj)
                #pragma unroll
                for (int i = 0; i < 4; ++i) {
                    const int row = bm + QMH[q] * 128 + wmr + fi * 16 + lg * 4 + i;
                    const int col = bn + QNH[q] * 128 + wnc + nj * 16 + l15;
                    if constexpr (std::is_same<TC, float>::value)
                        C[(long)row * ldc + col] = acc[q][fi][nj][i];
                    else
                        ((unsigned short*)C)[(long)row * ldc + col] = f2bf(acc[q][fi][nj][i]);
                }
}

// ---------------------------------------------------------------------------
// FUSED fragment-reuse GEMM + ropek (round 19, kept). Blocks 0..255: step 8.
// Blocks 256..511: step 9. Blocks 512..543: ropek (kf cols 128:192).
// ---------------------------------------------------------------------------
__global__ __launch_bounds__(256, 2) void gemmhw2_kernel(
    const bf16* __restrict__ A1, const bf16* __restrict__ B1, bf16* __restrict__ C1,
    int lda1, int ldb1, int ldc1, long aS1, long bS1, long cS1,
    const bf16* __restrict__ A2, const bf16* __restrict__ B2, bf16* __restrict__ C2,
    int lda2, int ldb2, int ldc2)
{
    const int b = blockIdx.x;
    if (b >= 512) {               // ---- fused ropek ----
        const int b2 = b - 512;
        const int i = threadIdx.x & 31;
        const int h0 = (threadIdx.x >> 5) * 4;
        const float inv = powf(10000.f, -(float)i / 32.f);
        for (int tt = 0; tt < 64; ++tt) {
            const int t = b2 * 64 + tt;
            const float x1 = __bfloat162float(A1[(long)t * lda1 + 512 + i]);
            const float x2 = __bfloat162float(A1[(long)t * lda1 + 544 + i]);
            float s, c;
            sincosf((float)t * inv, &s, &c);
            const bf16 o1 = __float2bfloat16(x1 * c - x2 * s);
            const bf16 o2 = __float2bfloat16(x2 * c + x1 * s);
            #pragma unroll
            for (int hh = 0; hh < 4; ++hh) {
                bf16* kb = C1 + ((long)(h0 + hh) * T_SEQ + t) * 192;
                kb[128 + i] = o1;
                kb[160 + i] = o2;
            }
        }
        return;
    }
    const bf16* A; const bf16* B; bf16* C;
    int lda, ldb, ldc, bm, bn;
    if (b < 256) {                    // step 8: k_nope[h] = ckv_n @ wkc[h]^T
        const int z = b >> 3;
        A = A1 + (long)z * aS1; B = B1 + (long)z * bS1; C = C1 + (long)z * cS1;
        lda = lda1; ldb = ldb1; ldc = ldc1;
        bm = (b & 7) * 256; bn = 0;
    } else {                          // step 9: vt = wvct @ ckv_n^T
        const int bb = b - 256;
        A = A2; B = B2; C = C2;
        lda = lda2; ldb = ldb2; ldc = ldc2;
        bm = (bb >> 4) * 256; bn = (bb & 15) * 128;
    }
    const int K = 512;
    __shared__ __align__(16) short As[2][256 * 32];
    __shared__ __align__(16) short Bs[2][128 * 32];
    const int tid = threadIdx.x, lane = tid & 63, w = tid >> 6;
    const int l15 = lane & 15, lg = lane >> 4;
    const int wm = w >> 1, wn = w & 1;
    const int sx = (lane & 7) ^ (lane >> 3);
    const int lrh = lane >> 3;
    const int srp = sx >> 2;
    const int scol = (sx & 3) * 8;
    const bf16* Ab = A + (long)bm * lda;
    const bf16* Bb = B + (long)bn * ldb;

    auto stage = [&](int buf, int k0) {
        #pragma unroll
        for (int jj = 0; jj < 4; ++jj) {
            const int j = w * 4 + jj;
            const int srow = 2 * (j * 8 + lrh) + srp;
            gload_lds16(Ab + (long)srow * lda + k0 + scol, &As[buf][j * 512]);
        }
        #pragma unroll
        for (int jj = 0; jj < 2; ++jj) {
            const int j = w * 2 + jj;
            const int srow = 2 * (j * 8 + lrh) + srp;
            gload_lds16(Bb + (long)srow * ldb + k0 + scol, &Bs[buf][j * 512]);
        }
    };

    const int rslot = ((((l15 & 1) << 2) | lg) ^ (l15 >> 1)) << 4;
    const int lrow_lo = l15 >> 1;
    f32x4 acc[8][4] = {};
    const int nt = K >> 5;
    stage(0, 0);
    for (int t = 0; t < nt; ++t) {
        if (t + 1 < nt) {
            stage((t + 1) & 1, (t + 1) << 5);
            asm volatile("s_waitcnt vmcnt(6)" ::: "memory");
        } else {
            asm volatile("s_waitcnt vmcnt(0)" ::: "memory");
        }
        __builtin_amdgcn_s_barrier();
        __builtin_amdgcn_sched_barrier(0);
        const char* Ap = (const char*)&As[t & 1][0];
        const char* Bp = (const char*)&Bs[t & 1][0];
        short8 af[8], bf[4];
        #pragma unroll
        for (int fi = 0; fi < 8; ++fi)
            af[fi] = *(const short8*)(Ap + (wm * 64 + fi * 8 + lrow_lo) * 128 + rslot);
        #pragma unroll
        for (int nj = 0; nj < 4; ++nj)
            bf[nj] = *(const short8*)(Bp + (wn * 32 + nj * 8 + lrow_lo) * 128 + rslot);
        #pragma unroll
        for (int fi = 0; fi < 8; ++fi)
            #pragma unroll
            for (int nj = 0; nj < 4; ++nj)
                acc[fi][nj] = __builtin_amdgcn_mfma_f32_16x16x32_bf16(
                    af[fi], bf[nj], acc[fi][nj], 0, 0, 0);
        asm volatile("s_waitcnt lgkmcnt(0)" ::: "memory");
        __builtin_amdgcn_sched_barrier(0);
        __builtin_amdgcn_s_barrier();
        __builtin_amdgcn_sched_barrier(0);
    }
    #pragma unroll
    for (int fi = 0; fi < 8; ++fi)
        #pragma unroll
        for (int nj = 0; nj < 4; ++nj)
            #pragma unroll
            for (int i = 0; i < 4; ++i) {
                const int row = bm + wm * 128 + fi * 16 + lg * 4 + i;
                const int col = bn + wn * 64 + nj * 16 + l15;
                ((unsigned short*)C)[(long)row * ldc + col] = f2bf(acc[fi][nj][i]);
            }
}

// ---------------------------------------------------------------------------
// Pipelined GEMM + fused wqb/wkc conversions (round 13, unchanged).
// ---------------------------------------------------------------------------
#define GW_NXT 17
#define GW_EXX 8
template <typename TC>
__global__ __launch_bounds__(512, 4) void gemm8w_kernel(
    const bf16* __restrict__ A, const bf16* __restrict__ B, TC* __restrict__ C,
    int K, int lda, int ldb, int ldc,
    const float* __restrict__ cv1in, bf16* __restrict__ cv1out, long n1v, float s1,
    const float* __restrict__ cv2in, bf16* __restrict__ cv2out, long n2v)
{
    const int tid = threadIdx.x;
    if (blockIdx.x >= GW_NXT) {   // ---- fused conversion blocks ----
        const int cb = (blockIdx.x - GW_NXT) * gridDim.y + blockIdx.y;
        const long stride = (long)GW_EXX * gridDim.y * 512;
        for (long v = (long)cb * 512 + tid; v < n1v + n2v; v += stride) {
            if (v < n1v) cvt8(cv1in, cv1out, v, s1);
            else         cvt8(cv2in, cv2out, v - n1v, 1.f);
        }
        return;
    }
    const int bm = blockIdx.y * 128, bn = blockIdx.x * 128;
    __shared__ __align__(16) short As[2][128 * 64];
    __shared__ __align__(16) short Bs[2][128 * 64];
    const int lane = tid & 63, w = tid >> 6;
    const int l15 = lane & 15, lg = lane >> 4;
    const int wm = w >> 1, wn = w & 1;
    const int c0 = w * 2, c1 = w * 2 + 1;
    const int srow0 = c0 * 8 + (lane >> 3), srow1 = c1 * 8 + (lane >> 3);
    const int scol = ((lane & 7) * 16) ^ ((lane >> 3) << 4);
    const bf16* Ab = A + (long)bm * lda;
    const bf16* Bb = B + (long)bn * ldb;

    auto stage = [&](int buf, int k0) {
        const char* ag = (const char*)(Ab + k0);
        const char* bg = (const char*)(Bb + k0);
        gload_lds16(ag + (long)srow0 * (lda * 2) + scol, &As[buf][c0 * 512]);
        gload_lds16(ag + (long)srow1 * (lda * 2) + scol, &As[buf][c1 * 512]);
        gload_lds16(bg + (long)srow0 * (ldb * 2) + scol, &Bs[buf][c0 * 512]);
        gload_lds16(bg + (long)srow1 * (ldb * 2) + scol, &Bs[buf][c1 * 512]);
    };

    const int swz = (l15 & 7) << 4;
    f32x4 acc[2][4] = {};
    const int nt = K >> 6;
    stage(0, 0);
    for (int t = 0; t < nt; ++t) {
        if (t + 1 < nt) {
            stage((t + 1) & 1, (t + 1) << 6);
            asm volatile("s_waitcnt vmcnt(4)" ::: "memory");
        } else {
            asm volatile("s_waitcnt vmcnt(0)" ::: "memory");
        }
        __builtin_amdgcn_s_barrier();
        __builtin_amdgcn_sched_barrier(0);
        const char* Ap = (const char*)&As[t & 1][0];
        const char* Bp = (const char*)&Bs[t & 1][0];
        short8 af[2][2], bfv[4][2];
        #pragma unroll
        for (int fi = 0; fi < 2; ++fi)
            #pragma unroll
            for (int ks = 0; ks < 2; ++ks)
                af[fi][ks] = *(const short8*)(Ap + (wm * 32 + fi * 16 + l15) * 128
                                              + ((ks * 64 + lg * 16) ^ swz));
        #pragma unroll
        for (int nj = 0; nj < 4; ++nj)
            #pragma unroll
            for (int ks = 0; ks < 2; ++ks)
                bfv[nj][ks] = *(const short8*)(Bp + (wn * 64 + nj * 16 + l15) * 128
                                               + ((ks * 64 + lg * 16) ^ swz));
        #pragma unroll
        for (int ks = 0; ks < 2; ++ks)
            #pragma unroll
            for (int fi = 0; fi < 2; ++fi)
                #pragma unroll
                for (int nj = 0; nj < 4; ++nj)
                    acc[fi][nj] = __builtin_amdgcn_mfma_f32_16x16x32_bf16(
                        af[fi][ks], bfv[nj][ks], acc[fi][nj], 0, 0, 0);
        asm volatile("s_waitcnt lgkmcnt(0)" ::: "memory");
        __builtin_amdgcn_sched_barrier(0);
        __builtin_amdgcn_s_barrier();
        __builtin_amdgcn_sched_barrier(0);
    }
    #pragma unroll
    for (int fi = 0; fi < 2; ++fi)
        #pragma unroll
        for (int nj = 0; nj < 4; ++nj)
            #pragma unroll
            for (int i = 0; i < 4; ++i) {
                const int row = bm + wm * 32 + fi * 16 + lg * 4 + i;
                const int col = bn + wn * 64 + nj * 16 + l15;
                if constexpr (std::is_same<TC, float>::value)
                    C[(long)row * ldc + col] = acc[fi][nj][i];
                else
                    ((unsigned short*)C)[(long)row * ldc + col] = f2bf(acc[fi][nj][i]);
            }
}

// ---------------------------------------------------------------------------
// Merged conversions + w_vc transpose (round 18, unchanged).
// ---------------------------------------------------------------------------
__global__ __launch_bounds__(256) void cvtall_kernel(
    const float* __restrict__ hid, bf16* __restrict__ hb,
    const float* __restrict__ wqa, const float* __restrict__ wkva,
    bf16* __restrict__ wqckv,
    const float* __restrict__ wvc, bf16* __restrict__ wvct)
{
    if (blockIdx.x >= 2048) {     // ---- w_vc transpose-convert tile ----
        const int idx = blockIdx.x - 2048;
        const int h = idx >> 6, d0 = ((idx >> 4) & 3) * 32, k0 = (idx & 15) * 32;
        __shared__ float t[32][33];
        const int r = threadIdx.x >> 5, c = threadIdx.x & 31;
        const float* ip = wvc + ((long)h * 512 + k0) * 128 + d0;
        #pragma unroll
        for (int it = 0; it < 4; ++it)
            t[r + 8 * it][c] = ip[(long)(r + 8 * it) * 128 + c];
        __syncthreads();
        bf16* op = wvct + ((long)h * 128 + d0) * 512 + k0;
        #pragma unroll
        for (int it = 0; it < 4; ++it)
            op[(long)(r + 8 * it) * 512 + c] = __float2bfloat16(t[c][r + 8 * it]);
        return;
    }
    const long N0 = (long)T_SEQ * 5120 / 8;
    const long N1 = N0 + (long)1536 * 5120 / 8;
    const long N2 = N1 + (long)576 * 5120 / 8;
    const long N3 = N2 + (long)64 * 5120 / 8;
    const long stride = (long)2048 * 256;
    for (long v = (long)blockIdx.x * 256 + threadIdx.x; v < N3; v += stride) {
        if (v < N0) cvt8(hid, hb, v, 1.f);
        else if (v < N1) cvt8(wqa, wqckv, v - N0, 1.f);
        else if (v < N2) cvt8(wkva, wqckv + (long)1536 * 5120, v - N1, 1.f);
        else {
            short8 z = {};
            *(short8*)(wqckv + (long)2112 * 5120 + (v - N2) * 8) = z;
        }
    }
}

// ---------------------------------------------------------------------------
__global__ __launch_bounds__(256) void rmsnorm2_kernel(
    bf16* __restrict__ x1, const float* __restrict__ w1, int C1,
    bf16* __restrict__ x2, const float* __restrict__ w2, int C2, int ld)
{
    bf16* row;
    const float* w;
    int C;
    if (blockIdx.x < 2048) { row = x1 + (long)blockIdx.x * ld; w = w1; C = C1; }
    else { row = x2 + (long)(blockIdx.x - 2048) * ld; w = w2; C = C2; }
    float ss = 0.f;
    for (int i = threadIdx.x; i < C; i += 256) {
        float v = __bfloat162float(row[i]);
        ss += v * v;
    }
    #pragma unroll
    for (int m = 1; m < 64; m <<= 1) ss += __shfl_xor(ss, m, 64);
    __shared__ float red[4];
    if ((threadIdx.x & 63) == 0) red[threadIdx.x >> 6] = ss;
    __syncthreads();
    ss = red[0] + red[1] + red[2] + red[3];
    float scale = rsqrtf(ss / (float)C + 1e-6f);
    for (int i = threadIdx.x; i < C; i += 256) {
        float v = __bfloat162float(row[i]);
        row[i] = __float2bfloat16(v * scale * w[i]);
    }
}

// ---------------------------------------------------------------------------
// Standalone rope on q (restored — in-attn rope cost +25 µs in r19).
// ---------------------------------------------------------------------------
__global__ __launch_bounds__(256) void ropeq_kernel(bf16* __restrict__ q)
{
    const int t = blockIdx.x;
    #pragma unroll
    for (int it = 0; it < 4; ++it) {
        const int pair = threadIdx.x + 256 * it;
        const int h = pair >> 5, i = pair & 31;
        bf16* base = q + ((long)t * NH + h) * 192;
        float x1 = __bfloat162float(base[128 + i]);
        float x2 = __bfloat162float(base[160 + i]);
        float inv = powf(10000.f, -(float)i / 32.f);
        float ang = (float)t * inv, s, c;
        sincosf(ang, &s, &c);
        base[128 + i] = __float2bfloat16(x1 * c - x2 * s);
        base[160 + i] = __float2bfloat16(x2 * c + x1 * s);
    }
}

// ---------------------------------------------------------------------------
// Flash attention + fused w_o conversion (round-18 exact body, (256,2)).
// ---------------------------------------------------------------------------
__global__ __launch_bounds__(256, 2) void attn_kernel(
    const bf16* __restrict__ Q,   // [T][H][192] scaled+roped
    const bf16* __restrict__ Kf,  // [H][T][192]
    const bf16* __restrict__ Vt,  // [H][128][T]  (V^T)
    bf16* __restrict__ O,         // [T][H*128]
    const float* __restrict__ WOin, bf16* __restrict__ WOout)
{
    if (blockIdx.x >= 512) {      // ---- fused w_o conversion ----
        const long base = ((long)blockIdx.x - 512) * 2048 + threadIdx.x;
        #pragma unroll
        for (int it = 0; it < 8; ++it)
            cvt8(WOin, WOout, base + (long)it * 256, 1.f);
        return;
    }
    const int lin = blockIdx.x;
    const int h = (lin & 7) + 8 * ((lin >> 3) & 3);
    const int qraw = lin >> 5;
    const int qblk = (qraw < 8) ? (2 * qraw) : (31 - 2 * qraw);
    const int q0 = qblk * 128;
    const int tid = threadIdx.x, lane = tid & 63, w = tid >> 6;
    const int l15 = lane & 15, lg = lane >> 4;
    const int qw = q0 + w * 32;
    __shared__ __align__(16) short Ks[64 * 192];
    __shared__ __align__(16) short Vs[128 * 64];

    int ksoff[6];
    #pragma unroll
    for (int j = 0; j < 6; ++j) {
        int o = (w * 6 + j) * 1024 + lane * 16;
        int row = o / 384, col = o % 384;
        ksoff[j] = row * 384 + (col ^ ((row & 7) << 4));
    }
    const int vrow8 = lane >> 3;
    const int vscol = ((lane & 7) * 16) ^ (vrow8 << 4);

    short8 qf[2][6];
    #pragma unroll
    for (int qi = 0; qi < 2; ++qi) {
        const bf16* qp = Q + (long)(qw + qi * 16 + l15) * (NH * 192) + (long)h * 192;
        #pragma unroll
        for (int c = 0; c < 6; ++c) qf[qi][c] = *(const short8*)(qp + c * 32 + lg * 8);
    }

    f32x4 oacc[2][8] = {};
    float mst[2] = {-INFINITY, -INFINITY};
    float lst[2] = {0.f, 0.f};

    const char* kbase0 = (const char*)Kf + (long)h * T_SEQ * 384;
    const char* vbase0 = (const char*)Vt + (long)h * 128 * (T_SEQ * 2);
    const int swz = (l15 & 7) << 4;

    for (int s0 = 0; s0 < q0 + 128; s0 += 64) {
        {   // stage K (24 KB) + V^T (16 KB) via global_load_lds, swizzled src
            const char* kb = kbase0 + (long)s0 * 384;
            #pragma unroll
            for (int j = 0; j < 6; ++j)
                gload_lds16(kb + ksoff[j], (char*)Ks + (w * 6 + j) * 1024);
            const char* vb = vbase0 + (long)s0 * 2 + vscol;
            #pragma unroll
            for (int j = 0; j < 4; ++j) {
                const int c = w * 4 + j;
                gload_lds16(vb + (long)(c * 8 + vrow8) * (T_SEQ * 2),
                            (char*)Vs + c * 1024);
            }
        }
        __syncthreads();
        if (s0 <= qw + 31) {
            f32x4 st[2][4] = {};
            __builtin_amdgcn_s_setprio(1);
            #pragma unroll
            for (int cb = 0; cb < 4; ++cb) {
                const int krow = cb * 16 + l15;
                #pragma unroll
                for (int c = 0; c < 6; ++c) {
                    short8 kfr = *(const short8*)((const char*)Ks + krow * 384
                                                  + ((c * 64 + lg * 16) ^ swz));
                    st[0][cb] = __builtin_amdgcn_mfma_f32_16x16x32_bf16(kfr, qf[0][c], st[0][cb], 0, 0, 0);
                    st[1][cb] = __builtin_amdgcn_mfma_f32_16x16x32_bf16(kfr, qf[1][c], st[1][cb], 0, 0, 0);
                }
            }
            __builtin_amdgcn_s_setprio(0);
            float pmaxv[2];
            #pragma unroll
            for (int qi = 0; qi < 2; ++qi) {
                const int qg = qw + qi * 16 + l15;
                float pmax = -INFINITY;
                #pragma unroll
                for (int cb = 0; cb < 4; ++cb)
                    #pragma unroll
                    for (int i = 0; i < 4; ++i) {
                        const int kv = s0 + cb * 16 + lg * 4 + i;
                        float v = (kv <= qg) ? st[qi][cb][i] : -INFINITY;
                        st[qi][cb][i] = v;
                        pmax = fmaxf(pmax, v);
                    }
                pmax = fmaxf(pmax, __shfl_xor(pmax, 16, 64));
                pmax = fmaxf(pmax, __shfl_xor(pmax, 32, 64));
                pmaxv[qi] = pmax;
            }
            const bool full = !__all((pmaxv[0] - mst[0] <= 8.f) &&
                                     (pmaxv[1] - mst[1] <= 8.f));
            short8 pb[2][2];
            #pragma unroll
            for (int qi = 0; qi < 2; ++qi) {
                float mm;
                if (full) {
                    const float newm = fmaxf(mst[qi], pmaxv[qi]);
                    mm = (newm == -INFINITY) ? 0.f : newm;
                    const float alpha = __expf(mst[qi] - mm);
                    lst[qi] *= alpha;
                    mst[qi] = newm;
                    #pragma unroll
                    for (int mb = 0; mb < 8; ++mb) oacc[qi][mb] *= alpha;
                } else {
                    mm = mst[qi];
                }
                float ps = 0.f;
                #pragma unroll
                for (int cb = 0; cb < 4; ++cb)
                    #pragma unroll
                    for (int i = 0; i < 4; ++i) {
                        const float e = __expf(st[qi][cb][i] - mm);
                        st[qi][cb][i] = e; ps += e;
                    }
                ps += __shfl_xor(ps, 16, 64);
                ps += __shfl_xor(ps, 32, 64);
                lst[qi] += ps;
                #pragma unroll
                for (int hh = 0; hh < 2; ++hh) {
                    unsigned pk[4];
                    #pragma unroll
                    for (int i = 0; i < 4; ++i)
                        pk[i] = (unsigned)f2bf(st[qi][2 * hh][i])
                              | ((unsigned)f2bf(st[qi][2 * hh + 1][i]) << 16);
                    #pragma unroll
                    for (int j = 0; j < 8; ++j) {
                        const int src = l15 + (((2 * lg + (j >> 2)) & 3) << 4);
                        const unsigned u = (unsigned)__shfl((int)pk[j & 3], src, 64);
                        pb[qi][hh][j] = (short)((lg >> 1) ? (u >> 16) : (u & 0xffffu));
                    }
                }
            }
            __builtin_amdgcn_s_setprio(1);
            #pragma unroll
            for (int mb = 0; mb < 8; ++mb) {
                const int vrow = mb * 16 + l15;
                #pragma unroll
                for (int hh = 0; hh < 2; ++hh) {
                    short8 vfr = *(const short8*)((const char*)Vs + vrow * 128
                                                  + ((hh * 64 + lg * 16) ^ swz));
                    oacc[0][mb] = __builtin_amdgcn_mfma_f32_16x16x32_bf16(vfr, pb[0][hh], oacc[0][mb], 0, 0, 0);
                    oacc[1][mb] = __builtin_amdgcn_mfma_f32_16x16x32_bf16(vfr, pb[1][hh], oacc[1][mb], 0, 0, 0);
                }
            }
            __builtin_amdgcn_s_setprio(0);
        }
        __syncthreads();
    }
    #pragma unroll
    for (int qi = 0; qi < 2; ++qi) {
        const float inv = 1.f / lst[qi];
        const int qg = qw + qi * 16 + l15;
        #pragma unroll
        for (int mb = 0; mb < 8; ++mb)
            #pragma unroll
            for (int i = 0; i < 4; ++i) {
                const int dv = mb * 16 + lg * 4 + i;
                O[(long)qg * (NH * 128) + h * 128 + dv] = __float2bfloat16(oacc[qi][mb][i] * inv);
            }
    }
}

// ---------------------------------------------------------------------------
extern "C" void kernel_launch(void* const* d_in, const int* in_sizes, int n_in,
                              void* d_out, int out_size, void* d_ws, size_t ws_size,
                              hipStream_t stream)
{
    const float* hidden    = (const float*)d_in[0];
    const float* w_q_a     = (const float*)d_in[2];
    const float* q_a_ln_w  = (const float*)d_in[3];
    const float* w_q_b     = (const float*)d_in[4];
    const float* w_kv_a    = (const float*)d_in[5];
    const float* kv_a_ln_w = (const float*)d_in[6];
    const float* w_kc      = (const float*)d_in[7];
    const float* w_vc      = (const float*)d_in[8];
    const float* w_o       = (const float*)d_in[9];
    float* out = (float*)d_out;

    // workspace layout (bf16 elements)
    bf16* qckv  = (bf16*)d_ws;                      // [2048][2176]: qa | ckv(640)
    bf16* qbuf  = qckv  + (long)T_SEQ * 2176;       // [2048][32][192]
    bf16* kf    = qbuf  + (long)T_SEQ * 6144;       // [32][2048][192]
    bf16* vt    = kf    + (long)NH * T_SEQ * 192;   // [4096][2048]  (V^T stacked)
    bf16* ov    = vt    + (long)NH * 128 * T_SEQ;   // [2048][4096]
    bf16* hb    = ov    + (long)T_SEQ * 4096;       // [2048][5120] hidden bf16
    bf16* wqckv = hb    + (long)T_SEQ * 5120;       // [2176][5120]
    bf16* wqb   = wqckv + (long)2176 * 5120;        // [6144][1536]
    bf16* wkc   = wqb   + (long)6144 * 1536;        // [32][128][512]
    bf16* wvct  = wkc   + (long)NH * 128 * 512;     // [4096][512]  (w_vc^T stacked)
    bf16* wo    = hb;   // alias: hb/wqckv/wqb region dead by then
    bf16* ckv   = qckv + 1536;                      // ckv rows, stride 2176

    // --- merged pre-GEMM conversions + w_vc transpose (one launch) ---
    cvtall_kernel<<<dim3(4096), 256, 0, stream>>>(
        hidden, hb, w_q_a, w_kv_a, wqckv, w_vc, wvct);

    // 1+5 merged: qckv = hb @ wqckv^T + fused wqb/wkc conversions
    gemm8w_kernel<bf16><<<dim3(GW_NXT + GW_EXX, 16, 1), 512, 0, stream>>>(
        hb, wqckv, qckv, 5120, 5120, 5120, 2176,
        w_q_b, wqb, (long)6144 * 1536 / 8, SCALE_F,
        w_kc, wkc, (long)NH * 128 * 512 / 8);
    // 2+6. merged rmsnorm
    rmsnorm2_kernel<<<dim3(4096), 256, 0, stream>>>(
        qckv, q_a_ln_w, 1536, ckv, kv_a_ln_w, 512, 2176);
    // 3. q = qa @ wqb^T   (M=2048, N=6144, K=1536) — 8-phase 256^2
    gemm8p_kernel<bf16><<<dim3(24, 8), 512, 131072, stream>>>(
        qckv, wqb, qbuf, 1536, 2176, 1536, 6144);
    // 4. rope q (standalone — in-attn fusion regressed in r19)
    ropeq_kernel<<<dim3(T_SEQ), 256, 0, stream>>>(qbuf);
    // 8+9+ropek FUSED: k_nope (256 blocks) + vt (256) + ropek (32 tail)
    gemmhw2_kernel<<<dim3(544), 256, 0, stream>>>(
        ckv, wkc, kf, 2176, 512, 192,
        0, (long)128 * 512, (long)T_SEQ * 192,
        wvct, ckv, vt, 512, 2176, 2048);
    // 10+11. attention (blocks 0..511) + fused w_o conversion (512..1791)
    attn_kernel<<<dim3(1792), 256, 0, stream>>>(qbuf, kf, vt, ov, w_o, wo);
    // 12. out = ov @ wo^T   (M=2048, N=5120, K=4096), fp32 out — 8-phase 256^2
    gemm8p_kernel<float><<<dim3(20, 8), 512, 131072, stream>>>(
        ov, wo, out, 4096, 4096, 4096, 5120);
}

// Round 21
// 420.560 us; speedup vs baseline: 1.0316x; 1.0316x over previous
//
#include <hip/hip_runtime.h>
#include <hip/hip_bf16.h>
#include <type_traits>

typedef __attribute__((ext_vector_type(8))) short short8;
typedef __attribute__((ext_vector_type(4))) float f32x4;
using bf16 = __hip_bfloat16;

#define T_SEQ 2048
#define NH 32
#define SCALE_F 0.07216878364870323f   // 192^-0.5

__device__ inline unsigned short f2bf(float f) {
    unsigned u = __builtin_bit_cast(unsigned, f);
    return (unsigned short)((u + 0x7fffu + ((u >> 16) & 1u)) >> 16);
}

__device__ inline void gload_lds16(const void* g, void* l) {
    __builtin_amdgcn_global_load_lds(
        (const __attribute__((address_space(1))) unsigned*)g,
        (__attribute__((address_space(3))) unsigned*)l, 16, 0, 0);
}

__device__ inline void cvt8(const float* in, bf16* out, long v, float scale) {
    f32x4 a = *(const f32x4*)(in + v * 8), b = *(const f32x4*)(in + v * 8 + 4);
    short8 r;
    r[0] = (short)f2bf(a[0] * scale); r[1] = (short)f2bf(a[1] * scale);
    r[2] = (short)f2bf(a[2] * scale); r[3] = (short)f2bf(a[3] * scale);
    r[4] = (short)f2bf(b[0] * scale); r[5] = (short)f2bf(b[1] * scale);
    r[6] = (short)f2bf(b[2] * scale); r[7] = (short)f2bf(b[3] * scale);
    *(short8*)(out + v * 8) = r;
}

// ---------------------------------------------------------------------------
// 8-phase 256x256 GEMM (m201 template port): C[M,N] = A[M,K] * B^T.
// BK=64, 8 waves (512 thr), 128 KB dynamic LDS.
// ---------------------------------------------------------------------------
template <typename TC>
__global__ __launch_bounds__(512, 2) void gemm8p_kernel(
    const bf16* __restrict__ A, const bf16* __restrict__ B, TC* __restrict__ C,
    int K, int lda, int ldb, int ldc)
{
    extern __shared__ char Lds[];   // 131072 bytes
    const int bm = blockIdx.y * 256, bn = blockIdx.x * 256;
    const int tid = threadIdx.x, lane = tid & 63, w = tid >> 6;
    const int l15 = lane & 15, lg = lane >> 4;
    const int wmr = (w >> 2) * 64;
    const int wnc = (w & 3) * 32;
    const int lrh = lane >> 3;
    const int scolb = ((lane & 7) * 16) ^ ((lane >> 3) << 4);
    const int rdswz = (l15 & 7) << 4;
    const bf16* Ab = A + (long)bm * lda;
    const bf16* Bb = B + (long)bn * ldb;
    const int nt = K >> 6;

    auto stage_half = [&](int tt, int isB, int h) {
        const int buf = tt & 1;
        const int k0 = (tt >= nt ? tt - nt : tt) << 6;
        const bf16* Base = isB ? Bb : Ab;
        const int ld = isB ? ldb : lda;
        const char* g = (const char*)Base
            + ((long)(h * 128 + w * 8 + lrh) * ld + k0) * 2 + scolb;
        char* l = Lds + buf * 65536 + isB * 32768 + h * 16384 + w * 1024;
        gload_lds16(g, l);
        gload_lds16(g + (long)128 * ld, l + 8192);
    };

    f32x4 acc[4][4][2] = {};
    stage_half(0, 0, 0); stage_half(0, 1, 1); stage_half(0, 0, 1);
    stage_half(0, 1, 0); stage_half(1, 0, 0); stage_half(1, 1, 1);
    asm volatile("s_waitcnt vmcnt(4)" ::: "memory");
    __builtin_amdgcn_s_barrier();

    for (int t = 0; t < nt; ++t) {
        const char* Bufp = Lds + (t & 1) * 65536;
        short8 aF[4][2], bF[2][2];
        #define ARD(mh, fi, ks) \
            (*(const short8*)(Bufp + (mh) * 16384 + (wmr + (fi) * 16 + l15) * 128 \
                              + (((ks) * 64 + lg * 16) ^ rdswz)))
        #define BRD(nh, nj, ks) \
            (*(const short8*)(Bufp + 32768 + (nh) * 16384 + (wnc + (nj) * 16 + l15) * 128 \
                              + (((ks) * 64 + lg * 16) ^ rdswz)))
        #define MFMA16(q) \
            __builtin_amdgcn_s_setprio(1); \
            _Pragma("unroll") for (int ks = 0; ks < 2; ++ks) \
            _Pragma("unroll") for (int fi = 0; fi < 4; ++fi) \
            _Pragma("unroll") for (int nj = 0; nj < 2; ++nj) \
                acc[q][fi][nj] = __builtin_amdgcn_mfma_f32_16x16x32_bf16( \
                    aF[fi][ks], bF[nj][ks], acc[q][fi][nj], 0, 0, 0); \
            __builtin_amdgcn_s_setprio(0);

        #pragma unroll
        for (int fi = 0; fi < 4; ++fi) { aF[fi][0] = ARD(0, fi, 0); aF[fi][1] = ARD(0, fi, 1); }
        #pragma unroll
        for (int nj = 0; nj < 2; ++nj) { bF[nj][0] = BRD(0, nj, 0); bF[nj][1] = BRD(0, nj, 1); }
        stage_half(t + 1, 0, 1);
        asm volatile("s_waitcnt lgkmcnt(8)" ::: "memory");
        __builtin_amdgcn_s_barrier();
        asm volatile("s_waitcnt lgkmcnt(0)" ::: "memory");
        __builtin_amdgcn_sched_barrier(0);
        MFMA16(0)
        __builtin_amdgcn_s_barrier();
        #pragma unroll
        for (int nj = 0; nj < 2; ++nj) { bF[nj][0] = BRD(1, nj, 0); bF[nj][1] = BRD(1, nj, 1); }
        stage_half(t + 1, 1, 0);
        __builtin_amdgcn_s_barrier();
        asm volatile("s_waitcnt lgkmcnt(0)" ::: "memory");
        __builtin_amdgcn_sched_barrier(0);
        MFMA16(1)
        __builtin_amdgcn_s_barrier();
        #pragma unroll
        for (int fi = 0; fi < 4; ++fi) { aF[fi][0] = ARD(1, fi, 0); aF[fi][1] = ARD(1, fi, 1); }
        stage_half(t + 2, 0, 0);
        __builtin_amdgcn_s_barrier();
        asm volatile("s_waitcnt lgkmcnt(0)" ::: "memory");
        __builtin_amdgcn_sched_barrier(0);
        MFMA16(2)
        __builtin_amdgcn_s_barrier();
        #pragma unroll
        for (int nj = 0; nj < 2; ++nj) { bF[nj][0] = BRD(0, nj, 0); bF[nj][1] = BRD(0, nj, 1); }
        stage_half(t + 2, 1, 1);
        __builtin_amdgcn_s_barrier();
        asm volatile("s_waitcnt lgkmcnt(0)" ::: "memory");
        __builtin_amdgcn_sched_barrier(0);
        MFMA16(3)
        asm volatile("s_waitcnt vmcnt(4)" ::: "memory");
        __builtin_amdgcn_s_barrier();
        #undef ARD
        #undef BRD
        #undef MFMA16
    }
    asm volatile("s_waitcnt vmcnt(0)" ::: "memory");
    const int QMH[4] = {0, 0, 1, 1}, QNH[4] = {0, 1, 1, 0};
    #pragma unroll
    for (int q = 0; q < 4; ++q)
        #pragma unroll
        for (int fi = 0; fi < 4; ++fi)
            #pragma unroll
            for (int nj = 0; nj < 2; ++nj)
                #pragma unroll
                for (int i = 0; i < 4; ++i) {
                    const int row = bm + QMH[q] * 128 + wmr + fi * 16 + lg * 4 + i;
                    const int col = bn + QNH[q] * 128 + wnc + nj * 16 + l15;
                    if constexpr (std::is_same<TC, float>::value)
                        C[(long)row * ldc + col] = acc[q][fi][nj][i];
                    else
                        ((unsigned short*)C)[(long)row * ldc + col] = f2bf(acc[q][fi][nj][i]);
                }
}

// ---------------------------------------------------------------------------
// FUSED fragment-reuse GEMM: steps 8 and 9 in one 512-block launch
// (round 18 exact — no ropek tail; serial-tail fusion cost ~13 µs in r19/r20).
// ---------------------------------------------------------------------------
__global__ __launch_bounds__(256, 2) void gemmhw2_kernel(
    const bf16* __restrict__ A1, const bf16* __restrict__ B1, bf16* __restrict__ C1,
    int lda1, int ldb1, int ldc1, long aS1, long bS1, long cS1,
    const bf16* __restrict__ A2, const bf16* __restrict__ B2, bf16* __restrict__ C2,
    int lda2, int ldb2, int ldc2)
{
    const int b = blockIdx.x;
    const bf16* A; const bf16* B; bf16* C;
    int lda, ldb, ldc, bm, bn;
    if (b < 256) {                    // step 8: k_nope[h] = ckv_n @ wkc[h]^T
        const int z = b >> 3;
        A = A1 + (long)z * aS1; B = B1 + (long)z * bS1; C = C1 + (long)z * cS1;
        lda = lda1; ldb = ldb1; ldc = ldc1;
        bm = (b & 7) * 256; bn = 0;
    } else {                          // step 9: vt = wvct @ ckv_n^T
        const int bb = b - 256;
        A = A2; B = B2; C = C2;
        lda = lda2; ldb = ldb2; ldc = ldc2;
        bm = (bb >> 4) * 256; bn = (bb & 15) * 128;
    }
    const int K = 512;
    __shared__ __align__(16) short As[2][256 * 32];
    __shared__ __align__(16) short Bs[2][128 * 32];
    const int tid = threadIdx.x, lane = tid & 63, w = tid >> 6;
    const int l15 = lane & 15, lg = lane >> 4;
    const int wm = w >> 1, wn = w & 1;
    const int sx = (lane & 7) ^ (lane >> 3);
    const int lrh = lane >> 3;
    const int srp = sx >> 2;
    const int scol = (sx & 3) * 8;
    const bf16* Ab = A + (long)bm * lda;
    const bf16* Bb = B + (long)bn * ldb;

    auto stage = [&](int buf, int k0) {
        #pragma unroll
        for (int jj = 0; jj < 4; ++jj) {
            const int j = w * 4 + jj;
            const int srow = 2 * (j * 8 + lrh) + srp;
            gload_lds16(Ab + (long)srow * lda + k0 + scol, &As[buf][j * 512]);
        }
        #pragma unroll
        for (int jj = 0; jj < 2; ++jj) {
            const int j = w * 2 + jj;
            const int srow = 2 * (j * 8 + lrh) + srp;
            gload_lds16(Bb + (long)srow * ldb + k0 + scol, &Bs[buf][j * 512]);
        }
    };

    const int rslot = ((((l15 & 1) << 2) | lg) ^ (l15 >> 1)) << 4;
    const int lrow_lo = l15 >> 1;
    f32x4 acc[8][4] = {};
    const int nt = K >> 5;
    stage(0, 0);
    for (int t = 0; t < nt; ++t) {
        if (t + 1 < nt) {
            stage((t + 1) & 1, (t + 1) << 5);
            asm volatile("s_waitcnt vmcnt(6)" ::: "memory");
        } else {
            asm volatile("s_waitcnt vmcnt(0)" ::: "memory");
        }
        __builtin_amdgcn_s_barrier();
        __builtin_amdgcn_sched_barrier(0);
        const char* Ap = (const char*)&As[t & 1][0];
        const char* Bp = (const char*)&Bs[t & 1][0];
        short8 af[8], bf[4];
        #pragma unroll
        for (int fi = 0; fi < 8; ++fi)
            af[fi] = *(const short8*)(Ap + (wm * 64 + fi * 8 + lrow_lo) * 128 + rslot);
        #pragma unroll
        for (int nj = 0; nj < 4; ++nj)
            bf[nj] = *(const short8*)(Bp + (wn * 32 + nj * 8 + lrow_lo) * 128 + rslot);
        #pragma unroll
        for (int fi = 0; fi < 8; ++fi)
            #pragma unroll
            for (int nj = 0; nj < 4; ++nj)
                acc[fi][nj] = __builtin_amdgcn_mfma_f32_16x16x32_bf16(
                    af[fi], bf[nj], acc[fi][nj], 0, 0, 0);
        asm volatile("s_waitcnt lgkmcnt(0)" ::: "memory");
        __builtin_amdgcn_sched_barrier(0);
        __builtin_amdgcn_s_barrier();
        __builtin_amdgcn_sched_barrier(0);
    }
    #pragma unroll
    for (int fi = 0; fi < 8; ++fi)
        #pragma unroll
        for (int nj = 0; nj < 4; ++nj)
            #pragma unroll
            for (int i = 0; i < 4; ++i) {
                const int row = bm + wm * 128 + fi * 16 + lg * 4 + i;
                const int col = bn + wn * 64 + nj * 16 + l15;
                ((unsigned short*)C)[(long)row * ldc + col] = f2bf(acc[fi][nj][i]);
            }
}

// ---------------------------------------------------------------------------
// Pipelined GEMM + fused wqb/wkc conversions (round 13, unchanged).
// ---------------------------------------------------------------------------
#define GW_NXT 17
#define GW_EXX 8
template <typename TC>
__global__ __launch_bounds__(512, 4) void gemm8w_kernel(
    const bf16* __restrict__ A, const bf16* __restrict__ B, TC* __restrict__ C,
    int K, int lda, int ldb, int ldc,
    const float* __restrict__ cv1in, bf16* __restrict__ cv1out, long n1v, float s1,
    const float* __restrict__ cv2in, bf16* __restrict__ cv2out, long n2v)
{
    const int tid = threadIdx.x;
    if (blockIdx.x >= GW_NXT) {   // ---- fused conversion blocks ----
        const int cb = (blockIdx.x - GW_NXT) * gridDim.y + blockIdx.y;
        const long stride = (long)GW_EXX * gridDim.y * 512;
        for (long v = (long)cb * 512 + tid; v < n1v + n2v; v += stride) {
            if (v < n1v) cvt8(cv1in, cv1out, v, s1);
            else         cvt8(cv2in, cv2out, v - n1v, 1.f);
        }
        return;
    }
    const int bm = blockIdx.y * 128, bn = blockIdx.x * 128;
    __shared__ __align__(16) short As[2][128 * 64];
    __shared__ __align__(16) short Bs[2][128 * 64];
    const int lane = tid & 63, w = tid >> 6;
    const int l15 = lane & 15, lg = lane >> 4;
    const int wm = w >> 1, wn = w & 1;
    const int c0 = w * 2, c1 = w * 2 + 1;
    const int srow0 = c0 * 8 + (lane >> 3), srow1 = c1 * 8 + (lane >> 3);
    const int scol = ((lane & 7) * 16) ^ ((lane >> 3) << 4);
    const bf16* Ab = A + (long)bm * lda;
    const bf16* Bb = B + (long)bn * ldb;

    auto stage = [&](int buf, int k0) {
        const char* ag = (const char*)(Ab + k0);
        const char* bg = (const char*)(Bb + k0);
        gload_lds16(ag + (long)srow0 * (lda * 2) + scol, &As[buf][c0 * 512]);
        gload_lds16(ag + (long)srow1 * (lda * 2) + scol, &As[buf][c1 * 512]);
        gload_lds16(bg + (long)srow0 * (ldb * 2) + scol, &Bs[buf][c0 * 512]);
        gload_lds16(bg + (long)srow1 * (ldb * 2) + scol, &Bs[buf][c1 * 512]);
    };

    const int swz = (l15 & 7) << 4;
    f32x4 acc[2][4] = {};
    const int nt = K >> 6;
    stage(0, 0);
    for (int t = 0; t < nt; ++t) {
        if (t + 1 < nt) {
            stage((t + 1) & 1, (t + 1) << 6);
            asm volatile("s_waitcnt vmcnt(4)" ::: "memory");
        } else {
            asm volatile("s_waitcnt vmcnt(0)" ::: "memory");
        }
        __builtin_amdgcn_s_barrier();
        __builtin_amdgcn_sched_barrier(0);
        const char* Ap = (const char*)&As[t & 1][0];
        const char* Bp = (const char*)&Bs[t & 1][0];
        short8 af[2][2], bfv[4][2];
        #pragma unroll
        for (int fi = 0; fi < 2; ++fi)
            #pragma unroll
            for (int ks = 0; ks < 2; ++ks)
                af[fi][ks] = *(const short8*)(Ap + (wm * 32 + fi * 16 + l15) * 128
                                              + ((ks * 64 + lg * 16) ^ swz));
        #pragma unroll
        for (int nj = 0; nj < 4; ++nj)
            #pragma unroll
            for (int ks = 0; ks < 2; ++ks)
                bfv[nj][ks] = *(const short8*)(Bp + (wn * 64 + nj * 16 + l15) * 128
                                               + ((ks * 64 + lg * 16) ^ swz));
        #pragma unroll
        for (int ks = 0; ks < 2; ++ks)
            #pragma unroll
            for (int fi = 0; fi < 2; ++fi)
                #pragma unroll
                for (int nj = 0; nj < 4; ++nj)
                    acc[fi][nj] = __builtin_amdgcn_mfma_f32_16x16x32_bf16(
                        af[fi][ks], bfv[nj][ks], acc[fi][nj], 0, 0, 0);
        asm volatile("s_waitcnt lgkmcnt(0)" ::: "memory");
        __builtin_amdgcn_sched_barrier(0);
        __builtin_amdgcn_s_barrier();
        __builtin_amdgcn_sched_barrier(0);
    }
    #pragma unroll
    for (int fi = 0; fi < 2; ++fi)
        #pragma unroll
        for (int nj = 0; nj < 4; ++nj)
            #pragma unroll
            for (int i = 0; i < 4; ++i) {
                const int row = bm + wm * 32 + fi * 16 + lg * 4 + i;
                const int col = bn + wn * 64 + nj * 16 + l15;
                if constexpr (std::is_same<TC, float>::value)
                    C[(long)row * ldc + col] = acc[fi][nj][i];
                else
                    ((unsigned short*)C)[(long)row * ldc + col] = f2bf(acc[fi][nj][i]);
            }
}

// ---------------------------------------------------------------------------
// Merged conversions + w_vc transpose (round 18, unchanged).
// ---------------------------------------------------------------------------
__global__ __launch_bounds__(256) void cvtall_kernel(
    const float* __restrict__ hid, bf16* __restrict__ hb,
    const float* __restrict__ wqa, const float* __restrict__ wkva,
    bf16* __restrict__ wqckv,
    const float* __restrict__ wvc, bf16* __restrict__ wvct)
{
    if (blockIdx.x >= 2048) {     // ---- w_vc transpose-convert tile ----
        const int idx = blockIdx.x - 2048;
        const int h = idx >> 6, d0 = ((idx >> 4) & 3) * 32, k0 = (idx & 15) * 32;
        __shared__ float t[32][33];
        const int r = threadIdx.x >> 5, c = threadIdx.x & 31;
        const float* ip = wvc + ((long)h * 512 + k0) * 128 + d0;
        #pragma unroll
        for (int it = 0; it < 4; ++it)
            t[r + 8 * it][c] = ip[(long)(r + 8 * it) * 128 + c];
        __syncthreads();
        bf16* op = wvct + ((long)h * 128 + d0) * 512 + k0;
        #pragma unroll
        for (int it = 0; it < 4; ++it)
            op[(long)(r + 8 * it) * 512 + c] = __float2bfloat16(t[c][r + 8 * it]);
        return;
    }
    const long N0 = (long)T_SEQ * 5120 / 8;
    const long N1 = N0 + (long)1536 * 5120 / 8;
    const long N2 = N1 + (long)576 * 5120 / 8;
    const long N3 = N2 + (long)64 * 5120 / 8;
    const long stride = (long)2048 * 256;
    for (long v = (long)blockIdx.x * 256 + threadIdx.x; v < N3; v += stride) {
        if (v < N0) cvt8(hid, hb, v, 1.f);
        else if (v < N1) cvt8(wqa, wqckv, v - N0, 1.f);
        else if (v < N2) cvt8(wkva, wqckv + (long)1536 * 5120, v - N1, 1.f);
        else {
            short8 z = {};
            *(short8*)(wqckv + (long)2112 * 5120 + (v - N2) * 8) = z;
        }
    }
}

// ---------------------------------------------------------------------------
__global__ __launch_bounds__(256) void rmsnorm2_kernel(
    bf16* __restrict__ x1, const float* __restrict__ w1, int C1,
    bf16* __restrict__ x2, const float* __restrict__ w2, int C2, int ld)
{
    bf16* row;
    const float* w;
    int C;
    if (blockIdx.x < 2048) { row = x1 + (long)blockIdx.x * ld; w = w1; C = C1; }
    else { row = x2 + (long)(blockIdx.x - 2048) * ld; w = w2; C = C2; }
    float ss = 0.f;
    for (int i = threadIdx.x; i < C; i += 256) {
        float v = __bfloat162float(row[i]);
        ss += v * v;
    }
    #pragma unroll
    for (int m = 1; m < 64; m <<= 1) ss += __shfl_xor(ss, m, 64);
    __shared__ float red[4];
    if ((threadIdx.x & 63) == 0) red[threadIdx.x >> 6] = ss;
    __syncthreads();
    ss = red[0] + red[1] + red[2] + red[3];
    float scale = rsqrtf(ss / (float)C + 1e-6f);
    for (int i = threadIdx.x; i < C; i += 256) {
        float v = __bfloat162float(row[i]);
        row[i] = __float2bfloat16(v * scale * w[i]);
    }
}

// ---------------------------------------------------------------------------
__global__ __launch_bounds__(256) void ropeq_kernel(bf16* __restrict__ q)
{
    const int t = blockIdx.x;
    #pragma unroll
    for (int it = 0; it < 4; ++it) {
        const int pair = threadIdx.x + 256 * it;
        const int h = pair >> 5, i = pair & 31;
        bf16* base = q + ((long)t * NH + h) * 192;
        float x1 = __bfloat162float(base[128 + i]);
        float x2 = __bfloat162float(base[160 + i]);
        float inv = powf(10000.f, -(float)i / 32.f);
        float ang = (float)t * inv, s, c;
        sincosf(ang, &s, &c);
        base[128 + i] = __float2bfloat16(x1 * c - x2 * s);
        base[160 + i] = __float2bfloat16(x2 * c + x1 * s);
    }
}

// ---------------------------------------------------------------------------
__global__ __launch_bounds__(1024) void ropek_kernel(
    const bf16* __restrict__ ckv, bf16* __restrict__ kf, int ld)
{
    const int t = blockIdx.x;
    const int h = threadIdx.x >> 5, i = threadIdx.x & 31;
    float x1 = __bfloat162float(ckv[(long)t * ld + 512 + i]);
    float x2 = __bfloat162float(ckv[(long)t * ld + 544 + i]);
    float inv = powf(10000.f, -(float)i / 32.f);
    float ang = (float)t * inv, s, c;
    sincosf(ang, &s, &c);
    bf16* kb = kf + ((long)h * T_SEQ + t) * 192;
    kb[128 + i] = __float2bfloat16(x1 * c - x2 * s);
    kb[160 + i] = __float2bfloat16(x2 * c + x1 * s);
}

// ---------------------------------------------------------------------------
// Flash attention + fused w_o conversion (round-18 exact body, (256,2)).
// ---------------------------------------------------------------------------
__global__ __launch_bounds__(256, 2) void attn_kernel(
    const bf16* __restrict__ Q,   // [T][H][192] scaled+roped
    const bf16* __restrict__ Kf,  // [H][T][192]
    const bf16* __restrict__ Vt,  // [H][128][T]  (V^T)
    bf16* __restrict__ O,         // [T][H*128]
    const float* __restrict__ WOin, bf16* __restrict__ WOout)
{
    if (blockIdx.x >= 512) {      // ---- fused w_o conversion ----
        const long base = ((long)blockIdx.x - 512) * 2048 + threadIdx.x;
        #pragma unroll
        for (int it = 0; it < 8; ++it)
            cvt8(WOin, WOout, base + (long)it * 256, 1.f);
        return;
    }
    const int lin = blockIdx.x;
    const int h = (lin & 7) + 8 * ((lin >> 3) & 3);
    const int qraw = lin >> 5;
    const int qblk = (qraw < 8) ? (2 * qraw) : (31 - 2 * qraw);
    const int q0 = qblk * 128;
    const int tid = threadIdx.x, lane = tid & 63, w = tid >> 6;
    const int l15 = lane & 15, lg = lane >> 4;
    const int qw = q0 + w * 32;
    __shared__ __align__(16) short Ks[64 * 192];
    __shared__ __align__(16) short Vs[128 * 64];

    int ksoff[6];
    #pragma unroll
    for (int j = 0; j < 6; ++j) {
        int o = (w * 6 + j) * 1024 + lane * 16;
        int row = o / 384, col = o % 384;
        ksoff[j] = row * 384 + (col ^ ((row & 7) << 4));
    }
    const int vrow8 = lane >> 3;
    const int vscol = ((lane & 7) * 16) ^ (vrow8 << 4);

    short8 qf[2][6];
    #pragma unroll
    for (int qi = 0; qi < 2; ++qi) {
        const bf16* qp = Q + (long)(qw + qi * 16 + l15) * (NH * 192) + (long)h * 192;
        #pragma unroll
        for (int c = 0; c < 6; ++c) qf[qi][c] = *(const short8*)(qp + c * 32 + lg * 8);
    }

    f32x4 oacc[2][8] = {};
    float mst[2] = {-INFINITY, -INFINITY};
    float lst[2] = {0.f, 0.f};

    const char* kbase0 = (const char*)Kf + (long)h * T_SEQ * 384;
    const char* vbase0 = (const char*)Vt + (long)h * 128 * (T_SEQ * 2);
    const int swz = (l15 & 7) << 4;

    for (int s0 = 0; s0 < q0 + 128; s0 += 64) {
        {   // stage K (24 KB) + V^T (16 KB) via global_load_lds, swizzled src
            const char* kb = kbase0 + (long)s0 * 384;
            #pragma unroll
            for (int j = 0; j < 6; ++j)
                gload_lds16(kb + ksoff[j], (char*)Ks + (w * 6 + j) * 1024);
            const char* vb = vbase0 + (long)s0 * 2 + vscol;
            #pragma unroll
            for (int j = 0; j < 4; ++j) {
                const int c = w * 4 + j;
                gload_lds16(vb + (long)(c * 8 + vrow8) * (T_SEQ * 2),
                            (char*)Vs + c * 1024);
            }
        }
        __syncthreads();
        if (s0 <= qw + 31) {
            f32x4 st[2][4] = {};
            __builtin_amdgcn_s_setprio(1);
            #pragma unroll
            for (int cb = 0; cb < 4; ++cb) {
                const int krow = cb * 16 + l15;
                #pragma unroll
                for (int c = 0; c < 6; ++c) {
                    short8 kfr = *(const short8*)((const char*)Ks + krow * 384
                                                  + ((c * 64 + lg * 16) ^ swz));
                    st[0][cb] = __builtin_amdgcn_mfma_f32_16x16x32_bf16(kfr, qf[0][c], st[0][cb], 0, 0, 0);
                    st[1][cb] = __builtin_amdgcn_mfma_f32_16x16x32_bf16(kfr, qf[1][c], st[1][cb], 0, 0, 0);
                }
            }
            __builtin_amdgcn_s_setprio(0);
            float pmaxv[2];
            #pragma unroll
            for (int qi = 0; qi < 2; ++qi) {
                const int qg = qw + qi * 16 + l15;
                float pmax = -INFINITY;
                #pragma unroll
                for (int cb = 0; cb < 4; ++cb)
                    #pragma unroll
                    for (int i = 0; i < 4; ++i) {
                        const int kv = s0 + cb * 16 + lg * 4 + i;
                        float v = (kv <= qg) ? st[qi][cb][i] : -INFINITY;
                        st[qi][cb][i] = v;
                        pmax = fmaxf(pmax, v);
                    }
                pmax = fmaxf(pmax, __shfl_xor(pmax, 16, 64));
                pmax = fmaxf(pmax, __shfl_xor(pmax, 32, 64));
                pmaxv[qi] = pmax;
            }
            const bool full = !__all((pmaxv[0] - mst[0] <= 8.f) &&
                                     (pmaxv[1] - mst[1] <= 8.f));
            short8 pb[2][2];
            #pragma unroll
            for (int qi = 0; qi < 2; ++qi) {
                float mm;
                if (full) {
                    const float newm = fmaxf(mst[qi], pmaxv[qi]);
                    mm = (newm == -INFINITY) ? 0.f : newm;
                    const float alpha = __expf(mst[qi] - mm);
                    lst[qi] *= alpha;
                    mst[qi] = newm;
                    #pragma unroll
                    for (int mb = 0; mb < 8; ++mb) oacc[qi][mb] *= alpha;
                } else {
                    mm = mst[qi];
                }
                float ps = 0.f;
                #pragma unroll
                for (int cb = 0; cb < 4; ++cb)
                    #pragma unroll
                    for (int i = 0; i < 4; ++i) {
                        const float e = __expf(st[qi][cb][i] - mm);
                        st[qi][cb][i] = e; ps += e;
                    }
                ps += __shfl_xor(ps, 16, 64);
                ps += __shfl_xor(ps, 32, 64);
                lst[qi] += ps;
                #pragma unroll
                for (int hh = 0; hh < 2; ++hh) {
                    unsigned pk[4];
                    #pragma unroll
                    for (int i = 0; i < 4; ++i)
                        pk[i] = (unsigned)f2bf(st[qi][2 * hh][i])
                              | ((unsigned)f2bf(st[qi][2 * hh + 1][i]) << 16);
                    #pragma unroll
                    for (int j = 0; j < 8; ++j) {
                        const int src = l15 + (((2 * lg + (j >> 2)) & 3) << 4);
                        const unsigned u = (unsigned)__shfl((int)pk[j & 3], src, 64);
                        pb[qi][hh][j] = (short)((lg >> 1) ? (u >> 16) : (u & 0xffffu));
                    }
                }
            }
            __builtin_amdgcn_s_setprio(1);
            #pragma unroll
            for (int mb = 0; mb < 8; ++mb) {
                const int vrow = mb * 16 + l15;
                #pragma unroll
                for (int hh = 0; hh < 2; ++hh) {
                    short8 vfr = *(const short8*)((const char*)Vs + vrow * 128
                                                  + ((hh * 64 + lg * 16) ^ swz));
                    oacc[0][mb] = __builtin_amdgcn_mfma_f32_16x16x32_bf16(vfr, pb[0][hh], oacc[0][mb], 0, 0, 0);
                    oacc[1][mb] = __builtin_amdgcn_mfma_f32_16x16x32_bf16(vfr, pb[1][hh], oacc[1][mb], 0, 0, 0);
                }
            }
            __builtin_amdgcn_s_setprio(0);
        }
        __syncthreads();
    }
    #pragma unroll
    for (int qi = 0; qi < 2; ++qi) {
        const float inv = 1.f / lst[qi];
        const int qg = qw + qi * 16 + l15;
        #pragma unroll
        for (int mb = 0; mb < 8; ++mb)
            #pragma unroll
            for (int i = 0; i < 4; ++i) {
                const int dv = mb * 16 + lg * 4 + i;
                O[(long)qg * (NH * 128) + h * 128 + dv] = __float2bfloat16(oacc[qi][mb][i] * inv);
            }
    }
}

// ---------------------------------------------------------------------------
extern "C" void kernel_launch(void* const* d_in, const int* in_sizes, int n_in,
                              void* d_out, int out_size, void* d_ws, size_t ws_size,
                              hipStream_t stream)
{
    const float* hidden    = (const float*)d_in[0];
    const float* w_q_a     = (const float*)d_in[2];
    const float* q_a_ln_w  = (const float*)d_in[3];
    const float* w_q_b     = (const float*)d_in[4];
    const float* w_kv_a    = (const float*)d_in[5];
    const float* kv_a_ln_w = (const float*)d_in[6];
    const float* w_kc      = (const float*)d_in[7];
    const float* w_vc      = (const float*)d_in[8];
    const float* w_o       = (const float*)d_in[9];
    float* out = (float*)d_out;

    // workspace layout (bf16 elements)
    bf16* qckv  = (bf16*)d_ws;                      // [2048][2176]: qa | ckv(640)
    bf16* qbuf  = qckv  + (long)T_SEQ * 2176;       // [2048][32][192]
    bf16* kf    = qbuf  + (long)T_SEQ * 6144;       // [32][2048][192]
    bf16* vt    = kf    + (long)NH * T_SEQ * 192;   // [4096][2048]  (V^T stacked)
    bf16* ov    = vt    + (long)NH * 128 * T_SEQ;   // [2048][4096]
    bf16* hb    = ov    + (long)T_SEQ * 4096;       // [2048][5120] hidden bf16
    bf16* wqckv = hb    + (long)T_SEQ * 5120;       // [2176][5120]
    bf16* wqb   = wqckv + (long)2176 * 5120;        // [6144][1536]
    bf16* wkc   = wqb   + (long)6144 * 1536;        // [32][128][512]
    bf16* wvct  = wkc   + (long)NH * 128 * 512;     // [4096][512]  (w_vc^T stacked)
    bf16* wo    = hb;   // alias: hb/wqckv/wqb region dead by then
    bf16* ckv   = qckv + 1536;                      // ckv rows, stride 2176

    // --- merged pre-GEMM conversions + w_vc transpose (one launch) ---
    cvtall_kernel<<<dim3(4096), 256, 0, stream>>>(
        hidden, hb, w_q_a, w_kv_a, wqckv, w_vc, wvct);

    // 1+5 merged: qckv = hb @ wqckv^T + fused wqb/wkc conversions
    gemm8w_kernel<bf16><<<dim3(GW_NXT + GW_EXX, 16, 1), 512, 0, stream>>>(
        hb, wqckv, qckv, 5120, 5120, 5120, 2176,
        w_q_b, wqb, (long)6144 * 1536 / 8, SCALE_F,
        w_kc, wkc, (long)NH * 128 * 512 / 8);
    // 2+6. merged rmsnorm
    rmsnorm2_kernel<<<dim3(4096), 256, 0, stream>>>(
        qckv, q_a_ln_w, 1536, ckv, kv_a_ln_w, 512, 2176);
    // 3. q = qa @ wqb^T   (M=2048, N=6144, K=1536) — 8-phase 256^2
    gemm8p_kernel<bf16><<<dim3(24, 8), 512, 131072, stream>>>(
        qckv, wqb, qbuf, 1536, 2176, 1536, 6144);
    // 4. rope q
    ropeq_kernel<<<dim3(T_SEQ), 256, 0, stream>>>(qbuf);
    // 7. rope k_pe -> kf[:,:,128:192] (wide standalone launch)
    ropek_kernel<<<dim3(T_SEQ), 1024, 0, stream>>>(ckv, kf, 2176);
    // 8+9 FUSED: k_nope (256 blocks) + vt (256 blocks) — 512 blocks, 2/CU
    gemmhw2_kernel<<<dim3(512), 256, 0, stream>>>(
        ckv, wkc, kf, 2176, 512, 192,
        0, (long)128 * 512, (long)T_SEQ * 192,
        wvct, ckv, vt, 512, 2176, 2048);
    // 10+11. attention (blocks 0..511) + fused w_o conversion (512..1791)
    attn_kernel<<<dim3(1792), 256, 0, stream>>>(qbuf, kf, vt, ov, w_o, wo);
    // 12. out = ov @ wo^T   (M=2048, N=5120, K=4096), fp32 out — 8-phase 256^2
    gemm8p_kernel<float><<<dim3(20, 8), 512, 131072, stream>>>(
        ov, wo, out, 4096, 4096, 4096, 5120);
}